// Round 1
// baseline (287.392 us; speedup 1.0000x reference)
//
#include <hip/hip_runtime.h>
#include <hip/hip_bf16.h>

#define B_  2
#define S_  2048
#define D_  1024
#define H_  16
#define HD_ 64
#define M_  (B_*S_)   // 4096

using bf16x8 = __attribute__((ext_vector_type(8))) short;
using f32x4  = __attribute__((ext_vector_type(4))) float;

static __device__ __forceinline__ ushort f2bf(float f) {
    __hip_bfloat16 h = __float2bfloat16(f);
    return *reinterpret_cast<ushort*>(&h);
}

// ---------------- convert fp32 -> bf16 (same layout) ----------------
__global__ void convert_f32_bf16(const float* __restrict__ src, ushort* __restrict__ dst, int n) {
    int i = (blockIdx.x * blockDim.x + threadIdx.x) * 4;
    if (i < n) {
        float4 v = *reinterpret_cast<const float4*>(src + i);
        ushort4 o;
        o.x = f2bf(v.x); o.y = f2bf(v.y); o.z = f2bf(v.z); o.w = f2bf(v.w);
        *reinterpret_cast<ushort4*>(dst + i) = o;
    }
}

// ------------- transpose fp32 [R][C] -> bf16 [C][R] -----------------
__global__ void transpose_f32_to_bf16(const float* __restrict__ src, ushort* __restrict__ dst,
                                      int R, int C) {
    __shared__ float t[32][33];
    int c0 = blockIdx.x * 32, r0 = blockIdx.y * 32;
    int tx = threadIdx.x, ty = threadIdx.y;
    #pragma unroll
    for (int i = 0; i < 4; i++)
        t[ty + i*8][tx] = src[(size_t)(r0 + ty + i*8) * C + c0 + tx];
    __syncthreads();
    #pragma unroll
    for (int i = 0; i < 4; i++)
        dst[(size_t)(c0 + ty + i*8) * R + r0 + tx] = f2bf(t[tx][ty + i*8]);
}

// ---------------- GEMM: C = A(bf16 [M][K]) * Bt(bf16 [N][K])^T ----------------
// MODE 0: QKV epilogue (scatter to [b][h][s][hd] bf16, Q pre-scaled by 1/8, +bias)
// MODE 1: fp32 out [M][N] + bias
template<int MODE>
__launch_bounds__(256, 2)
__global__ void gemm_bt(const ushort* __restrict__ A, const ushort* __restrict__ Bt,
                        int Mdim, int Ndim, int Kdim,
                        ushort* __restrict__ qout, ushort* __restrict__ kout, ushort* __restrict__ vout,
                        const float* __restrict__ bq, const float* __restrict__ bk, const float* __restrict__ bv,
                        float* __restrict__ out, const float* __restrict__ bias)
{
    __shared__ __align__(16) ushort As[128][40];   // +8 pad: 2-way-max bank aliasing
    __shared__ __align__(16) ushort Bs[128][40];
    const int tid  = threadIdx.x;
    const int lane = tid & 63, wave = tid >> 6;
    const int wm = wave & 1, wn = wave >> 1;       // 2x2 waves -> 64x64 each
    const int m0 = blockIdx.y * 128, n0 = blockIdx.x * 128;
    const int g = lane >> 4, c = lane & 15;

    f32x4 acc[4][4];
    #pragma unroll
    for (int i = 0; i < 4; i++)
        #pragma unroll
        for (int j = 0; j < 4; j++) acc[i][j] = (f32x4){0.f, 0.f, 0.f, 0.f};

    const int ldrow = tid >> 2;       // 0..63
    const int ldc   = (tid & 3) * 8;  // 0,8,16,24

    for (int kt = 0; kt < Kdim; kt += 32) {
        #pragma unroll
        for (int p = 0; p < 2; p++) {
            int r = ldrow + p * 64;
            *reinterpret_cast<uint4*>(&As[r][ldc]) =
                *reinterpret_cast<const uint4*>(A  + (size_t)(m0 + r) * Kdim + kt + ldc);
            *reinterpret_cast<uint4*>(&Bs[r][ldc]) =
                *reinterpret_cast<const uint4*>(Bt + (size_t)(n0 + r) * Kdim + kt + ldc);
        }
        __syncthreads();
        bf16x8 af[4], bfr[4];
        #pragma unroll
        for (int t = 0; t < 4; t++) {
            af[t]  = *reinterpret_cast<const bf16x8*>(&As[wm*64 + t*16 + c][g*8]);
            bfr[t] = *reinterpret_cast<const bf16x8*>(&Bs[wn*64 + t*16 + c][g*8]);
        }
        #pragma unroll
        for (int i = 0; i < 4; i++)
            #pragma unroll
            for (int j = 0; j < 4; j++)
                acc[i][j] = __builtin_amdgcn_mfma_f32_16x16x32_bf16(af[i], bfr[j], acc[i][j], 0, 0, 0);
        __syncthreads();
    }

    #pragma unroll
    for (int i = 0; i < 4; i++) {
      #pragma unroll
      for (int j = 0; j < 4; j++) {
        #pragma unroll
        for (int r = 0; r < 4; r++) {
            int row = m0 + wm*64 + i*16 + g*4 + r;   // C/D: row=(lane>>4)*4+reg
            int col = n0 + wn*64 + j*16 + c;         //      col=lane&15
            float v = acc[i][j][r];
            if (MODE == 0) {
                int which = col >> 10;               // 0=q 1=k 2=v
                int cc = col & 1023;
                int b = row >> 11, s = row & 2047;
                int h = cc >> 6, hd = cc & 63;
                size_t dst = (((size_t)(b*H_ + h)) * S_ + s) * HD_ + hd;
                if (which == 0)      qout[dst] = f2bf((v + bq[cc]) * 0.125f); // att_scale folded in
                else if (which == 1) kout[dst] = f2bf(v + bk[cc]);
                else                 vout[dst] = f2bf(v + bv[cc]);
            } else {
                out[(size_t)row * Ndim + col] = v + bias[col];
            }
        }
      }
    }
}

// ---------------- flash attention, one (b,h, 128 q-rows) per block ----------------
__launch_bounds__(256, 2)
__global__ void attn_kernel(const ushort* __restrict__ Q, const ushort* __restrict__ K,
                            const ushort* __restrict__ V, ushort* __restrict__ O)
{
    __shared__ __align__(16) ushort Ks[128][72];    // keys x hd, pad->2-way max
    __shared__ __align__(16) ushort Vs[128][72];
    __shared__ __align__(16) ushort Ps[128][136];   // P round-trip (C-layout -> A-layout)
    const int tid = threadIdx.x, lane = tid & 63, w = tid >> 6;
    const int g = lane >> 4, c = lane & 15;
    const int bh = blockIdx.y;
    const int q0 = blockIdx.x * 128;
    const size_t base = (size_t)bh * S_ * HD_;

    // Q A-fragments live in registers for the whole kernel (Q pre-scaled by 1/8)
    bf16x8 aq[2][2];
    #pragma unroll
    for (int rt = 0; rt < 2; rt++)
        #pragma unroll
        for (int ks = 0; ks < 2; ks++)
            aq[rt][ks] = *reinterpret_cast<const bf16x8*>(
                Q + base + (size_t)(q0 + w*32 + rt*16 + c) * HD_ + ks*32 + g*8);

    f32x4 acc_o[2][4];
    float m_i[2][4], l_i[2][4];
    #pragma unroll
    for (int rt = 0; rt < 2; rt++)
        #pragma unroll
        for (int r = 0; r < 4; r++) {
            acc_o[rt][r] = (f32x4){0.f, 0.f, 0.f, 0.f};
            m_i[rt][r] = -INFINITY; l_i[rt][r] = 0.f;
        }

    const int sr = tid >> 3;        // 0..31
    const int sc = (tid & 7) * 8;   // 0..56

    for (int kt = 0; kt < S_; kt += 128) {
        #pragma unroll
        for (int p = 0; p < 4; p++) {
            int r = sr + p * 32;
            *reinterpret_cast<uint4*>(&Ks[r][sc]) =
                *reinterpret_cast<const uint4*>(K + base + (size_t)(kt + r) * HD_ + sc);
            *reinterpret_cast<uint4*>(&Vs[r][sc]) =
                *reinterpret_cast<const uint4*>(V + base + (size_t)(kt + r) * HD_ + sc);
        }
        __syncthreads();

        // S = Q K^T : this wave's 32 q-rows x 128 keys
        f32x4 accs[2][8];
        #pragma unroll
        for (int rt = 0; rt < 2; rt++)
            #pragma unroll
            for (int ct = 0; ct < 8; ct++) accs[rt][ct] = (f32x4){0.f, 0.f, 0.f, 0.f};
        #pragma unroll
        for (int ks = 0; ks < 2; ks++) {
            bf16x8 bk_[8];
            #pragma unroll
            for (int ct = 0; ct < 8; ct++)
                bk_[ct] = *reinterpret_cast<const bf16x8*>(&Ks[ct*16 + c][ks*32 + g*8]);
            #pragma unroll
            for (int rt = 0; rt < 2; rt++)
                #pragma unroll
                for (int ct = 0; ct < 8; ct++)
                    accs[rt][ct] = __builtin_amdgcn_mfma_f32_16x16x32_bf16(aq[rt][ks], bk_[ct], accs[rt][ct], 0, 0, 0);
        }

        // online softmax (rows owned per lane-group; reduce across the 16 cols)
        #pragma unroll
        for (int rt = 0; rt < 2; rt++) {
            float mx[4], rs[4], alpha[4];
            #pragma unroll
            for (int r = 0; r < 4; r++) {
                float m_ = accs[rt][0][r];
                #pragma unroll
                for (int ct = 1; ct < 8; ct++) m_ = fmaxf(m_, accs[rt][ct][r]);
                #pragma unroll
                for (int off = 1; off < 16; off <<= 1) m_ = fmaxf(m_, __shfl_xor(m_, off));
                float mn = fmaxf(m_i[rt][r], m_);
                alpha[r] = __expf(m_i[rt][r] - mn);
                m_i[rt][r] = mn;
                mx[r] = mn; rs[r] = 0.f;
            }
            #pragma unroll
            for (int ct = 0; ct < 8; ct++)
                #pragma unroll
                for (int r = 0; r < 4; r++) {
                    float p = __expf(accs[rt][ct][r] - mx[r]);
                    rs[r] += p;
                    Ps[w*32 + rt*16 + g*4 + r][ct*16 + c] = f2bf(p);
                }
            #pragma unroll
            for (int r = 0; r < 4; r++) {
                float t = rs[r];
                #pragma unroll
                for (int off = 1; off < 16; off <<= 1) t += __shfl_xor(t, off);
                l_i[rt][r] = l_i[rt][r] * alpha[r] + t;
                #pragma unroll
                for (int ct = 0; ct < 4; ct++) acc_o[rt][ct][r] *= alpha[r];
            }
        }
        // no barrier needed: each wave reads back only its own Ps rows

        // O += P V
        #pragma unroll
        for (int ks = 0; ks < 4; ks++) {
            bf16x8 ap[2];
            #pragma unroll
            for (int rt = 0; rt < 2; rt++)
                ap[rt] = *reinterpret_cast<const bf16x8*>(&Ps[w*32 + rt*16 + c][ks*32 + g*8]);
            #pragma unroll
            for (int ct = 0; ct < 4; ct++) {
                bf16x8 bv_;
                #pragma unroll
                for (int j = 0; j < 8; j++)
                    ((ushort*)&bv_)[j] = Vs[ks*32 + g*8 + j][ct*16 + c];  // scalar reads (round-2 target)
                #pragma unroll
                for (int rt = 0; rt < 2; rt++)
                    acc_o[rt][ct] = __builtin_amdgcn_mfma_f32_16x16x32_bf16(ap[rt], bv_, acc_o[rt][ct], 0, 0, 0);
            }
        }
        __syncthreads();   // protect Ks/Vs (and Ps) before next tile's staging
    }

    const int b = bh >> 4, h = bh & 15;
    #pragma unroll
    for (int rt = 0; rt < 2; rt++)
        #pragma unroll
        for (int ct = 0; ct < 4; ct++)
            #pragma unroll
            for (int r = 0; r < 4; r++) {
                int s = q0 + w*32 + rt*16 + g*4 + r;
                int col = h*64 + ct*16 + c;
                O[(size_t)(b*S_ + s) * 1024 + col] = f2bf(acc_o[rt][ct][r] / l_i[rt][r]);
            }
}

extern "C" void kernel_launch(void* const* d_in, const int* in_sizes, int n_in,
                              void* d_out, int out_size, void* d_ws, size_t ws_size,
                              hipStream_t stream)
{
    const float* x  = (const float*)d_in[0];
    const float* wq = (const float*)d_in[1];
    const float* bq = (const float*)d_in[2];
    const float* wk = (const float*)d_in[3];
    const float* bk = (const float*)d_in[4];
    const float* wv = (const float*)d_in[5];
    const float* bv = (const float*)d_in[6];
    const float* wo = (const float*)d_in[7];
    const float* bo = (const float*)d_in[8];
    float* out = (float*)d_out;

    char* ws = (char*)d_ws;
    ushort* xb    = (ushort*)(ws);                      // 8 MB  x as bf16
    ushort* wqkvT = (ushort*)(ws + (8ull  << 20));      // 6 MB  [3072][1024] bf16
    ushort* woT   = (ushort*)(ws + (14ull << 20));      // 2 MB  [1024][1024] bf16
    ushort* qw    = (ushort*)(ws + (16ull << 20));      // 8 MB  [b][h][s][hd]
    ushort* kw    = (ushort*)(ws + (24ull << 20));      // 8 MB
    ushort* vw    = (ushort*)(ws + (32ull << 20));      // 8 MB
    ushort* ao    = (ushort*)(ws + (40ull << 20));      // 8 MB  attn out [4096][1024]

    convert_f32_bf16<<<4096, 256, 0, stream>>>(x, xb, M_ * D_);
    dim3 tb(32, 8);
    transpose_f32_to_bf16<<<dim3(32, 32), tb, 0, stream>>>(wq, wqkvT,               1024, 1024);
    transpose_f32_to_bf16<<<dim3(32, 32), tb, 0, stream>>>(wk, wqkvT + 1024*1024,   1024, 1024);
    transpose_f32_to_bf16<<<dim3(32, 32), tb, 0, stream>>>(wv, wqkvT + 2*1024*1024, 1024, 1024);
    transpose_f32_to_bf16<<<dim3(32, 32), tb, 0, stream>>>(wo, woT,                 1024, 1024);

    // QKV: M=4096, N=3072, K=1024
    gemm_bt<0><<<dim3(24, 32), 256, 0, stream>>>(xb, wqkvT, M_, 3072, 1024,
                                                 qw, kw, vw, bq, bk, bv, nullptr, nullptr);
    // attention: 16 q-tiles x 32 (b,h)
    attn_kernel<<<dim3(16, 32), 256, 0, stream>>>(qw, kw, vw, ao);
    // out proj: M=4096, N=1024, K=1024
    gemm_bt<1><<<dim3(8, 32), 256, 0, stream>>>(ao, woT, M_, 1024, 1024,
                                                nullptr, nullptr, nullptr, nullptr, nullptr, nullptr,
                                                out, bo);
}

// Round 2
// 256.625 us; speedup vs baseline: 1.1199x; 1.1199x over previous
//
#include <hip/hip_runtime.h>
#include <hip/hip_bf16.h>

#define B_  2
#define S_  2048
#define D_  1024
#define H_  16
#define HD_ 64
#define M_  (B_*S_)   // 4096

using bf16x8 = __attribute__((ext_vector_type(8))) short;
using f32x4  = __attribute__((ext_vector_type(4))) float;

static __device__ __forceinline__ ushort f2bf(float f) {
    __hip_bfloat16 h = __float2bfloat16(f);
    return *reinterpret_cast<ushort*>(&h);
}

// async global->LDS, 16B per lane; LDS dest = wave-uniform base + lane*16
#define GLDS16(gp, lp) __builtin_amdgcn_global_load_lds( \
    (const __attribute__((address_space(1))) void*)(gp), \
    (__attribute__((address_space(3))) void*)(lp), 16, 0, 0)

// ---------------- convert fp32 -> bf16 (same layout) ----------------
__global__ void convert_f32_bf16(const float* __restrict__ src, ushort* __restrict__ dst, int n) {
    int i = (blockIdx.x * blockDim.x + threadIdx.x) * 4;
    if (i < n) {
        float4 v = *reinterpret_cast<const float4*>(src + i);
        ushort4 o;
        o.x = f2bf(v.x); o.y = f2bf(v.y); o.z = f2bf(v.z); o.w = f2bf(v.w);
        *reinterpret_cast<ushort4*>(dst + i) = o;
    }
}

// ------------- transpose fp32 [R][C] -> bf16 [C][R] -----------------
__global__ void transpose_f32_to_bf16(const float* __restrict__ src, ushort* __restrict__ dst,
                                      int R, int C) {
    __shared__ float t[32][33];
    int c0 = blockIdx.x * 32, r0 = blockIdx.y * 32;
    int tx = threadIdx.x, ty = threadIdx.y;
    #pragma unroll
    for (int i = 0; i < 4; i++)
        t[ty + i*8][tx] = src[(size_t)(r0 + ty + i*8) * C + c0 + tx];
    __syncthreads();
    #pragma unroll
    for (int i = 0; i < 4; i++)
        dst[(size_t)(c0 + ty + i*8) * R + r0 + tx] = f2bf(t[tx][ty + i*8]);
}

// ------------- transpose bf16 V [bh][s][hd] -> [bh][hd][s] ----------
__global__ void transpose_v(const ushort* __restrict__ src, ushort* __restrict__ dst) {
    __shared__ ushort t[64][72];   // row stride 144B (16B-divisible)
    int bh = blockIdx.y, s0 = blockIdx.x * 64;
    #pragma unroll
    for (int p = 0; p < 2; p++) {
        int idx = threadIdx.x + p * 256;        // 0..511
        int r = idx >> 3, cu = (idx & 7) * 8;   // r = s-row 0..63, cu = hd 0..56
        uint4 v = *reinterpret_cast<const uint4*>(src + (size_t)bh * 131072 + (size_t)(s0 + r) * 64 + cu);
        ushort tmp[8];
        *reinterpret_cast<uint4*>(tmp) = v;
        #pragma unroll
        for (int j = 0; j < 8; j++) t[cu + j][r] = tmp[j];
    }
    __syncthreads();
    #pragma unroll
    for (int p = 0; p < 2; p++) {
        int idx = threadIdx.x + p * 256;
        int r = idx >> 3, cu = (idx & 7) * 8;   // r = hd 0..63, cu = s 0..56
        *reinterpret_cast<uint4*>(dst + (size_t)bh * 131072 + (size_t)r * S_ + s0 + cu) =
            *reinterpret_cast<uint4*>(&t[r][cu]);
    }
}

// ---------------- GEMM: C = A(bf16 [M][K]) * Bt(bf16 [N][K])^T ----------------
// m97-style: unpadded LDS tiles + global_load_lds width-16 staging.
// MODE 0: QKV epilogue (scatter, Q pre-scaled by 0.125*log2e, +bias)
// MODE 1: fp32 out [M][N] + bias
template<int MODE>
__launch_bounds__(256, 2)
__global__ void gemm_bt(const ushort* __restrict__ A, const ushort* __restrict__ Bt,
                        int Mdim, int Ndim, int Kdim,
                        ushort* __restrict__ qout, ushort* __restrict__ kout, ushort* __restrict__ vout,
                        const float* __restrict__ bq, const float* __restrict__ bk, const float* __restrict__ bv,
                        float* __restrict__ out, const float* __restrict__ bias)
{
    __shared__ __align__(16) ushort As[128][32];   // unpadded: global_load_lds order
    __shared__ __align__(16) ushort Bs[128][32];
    const int tid  = threadIdx.x;
    const int lane = tid & 63, wave = tid >> 6;
    const int wm = wave & 1, wn = wave >> 1;       // 2x2 waves -> 64x64 each
    const int m0 = blockIdx.y * 128, n0 = blockIdx.x * 128;
    const int g = lane >> 4, c = lane & 15;

    f32x4 acc[4][4];
    #pragma unroll
    for (int i = 0; i < 4; i++)
        #pragma unroll
        for (int j = 0; j < 4; j++) acc[i][j] = (f32x4){0.f, 0.f, 0.f, 0.f};

    const int lrow = lane >> 2;       // 0..15 within 16-row chunk
    const int lcol = (lane & 3) * 8;  // ushort col 0,8,16,24

    for (int kt = 0; kt < Kdim; kt += 32) {
        // 8 chunks of 16 rows each for A and B; wave w stages chunks {w, w+4}
        #pragma unroll
        for (int p = 0; p < 2; p++) {
            int ch = wave + p * 4;
            GLDS16(A  + (size_t)(m0 + ch*16 + lrow) * Kdim + kt + lcol, &As[ch*16][0]);
            GLDS16(Bt + (size_t)(n0 + ch*16 + lrow) * Kdim + kt + lcol, &Bs[ch*16][0]);
        }
        __syncthreads();
        bf16x8 af[4], bfr[4];
        #pragma unroll
        for (int t = 0; t < 4; t++) {
            af[t]  = *reinterpret_cast<const bf16x8*>(&As[wm*64 + t*16 + c][g*8]);
            bfr[t] = *reinterpret_cast<const bf16x8*>(&Bs[wn*64 + t*16 + c][g*8]);
        }
        #pragma unroll
        for (int i = 0; i < 4; i++)
            #pragma unroll
            for (int j = 0; j < 4; j++)
                acc[i][j] = __builtin_amdgcn_mfma_f32_16x16x32_bf16(af[i], bfr[j], acc[i][j], 0, 0, 0);
        __syncthreads();
    }

    const float qscale = 0.125f * 1.4426950408889634f;  // att_scale * log2e (exp2 softmax)
    #pragma unroll
    for (int i = 0; i < 4; i++) {
      #pragma unroll
      for (int j = 0; j < 4; j++) {
        #pragma unroll
        for (int r = 0; r < 4; r++) {
            int row = m0 + wm*64 + i*16 + g*4 + r;   // C/D: row=(lane>>4)*4+reg
            int col = n0 + wn*64 + j*16 + c;         //      col=lane&15
            float v = acc[i][j][r];
            if (MODE == 0) {
                int which = col >> 10;               // 0=q 1=k 2=v
                int cc = col & 1023;
                int b = row >> 11, s = row & 2047;
                int h = cc >> 6, hd = cc & 63;
                size_t dst = (((size_t)(b*H_ + h)) * S_ + s) * HD_ + hd;
                if (which == 0)      qout[dst] = f2bf((v + bq[cc]) * qscale);
                else if (which == 1) kout[dst] = f2bf(v + bk[cc]);
                else                 vout[dst] = f2bf(v + bv[cc]);
            } else {
                out[(size_t)row * Ndim + col] = v + bias[col];
            }
        }
      }
    }
}

// ---------------- flash attention, one (b,h, 128 q-rows) per block ----------------
// S^T = K·Q^T  (C/D: row = key (4-consec regs), col = q (lane)), so P packs into
// Ps[q][key] with ds_write_b64; PV reads P (A-frag) and Vt (B-frag) as ds_read_b128.
__launch_bounds__(256, 2)
__global__ void attn_kernel(const ushort* __restrict__ Q, const ushort* __restrict__ K,
                            const ushort* __restrict__ Vt, ushort* __restrict__ O)
{
    __shared__ __align__(16) ushort Ks [128][72];   // [key][hd]   stride 144B
    __shared__ __align__(16) ushort Vts[64][136];   // [hd][key]   stride 272B
    __shared__ __align__(16) ushort Ps [128][136];  // [q][key]    stride 272B
    const int tid = threadIdx.x, lane = tid & 63, w = tid >> 6;
    const int g = lane >> 4, c = lane & 15;
    const int bh = blockIdx.y;
    const int q0 = blockIdx.x * 128;
    const size_t kbase = (size_t)bh * S_ * HD_;   // Q,K: [bh][s][hd]
    const size_t vbase = (size_t)bh * HD_ * S_;   // Vt:  [bh][hd][s]

    // Q B-fragments (pre-scaled by 0.125*log2e) live in registers
    bf16x8 qf[2][2];
    #pragma unroll
    for (int sub = 0; sub < 2; sub++)
        #pragma unroll
        for (int ks = 0; ks < 2; ks++)
            qf[sub][ks] = *reinterpret_cast<const bf16x8*>(
                Q + kbase + (size_t)(q0 + w*32 + sub*16 + c) * HD_ + ks*32 + g*8);

    f32x4 acc_o[2][4];
    float m_i[2], l_i[2];
    #pragma unroll
    for (int sub = 0; sub < 2; sub++) {
        m_i[sub] = -INFINITY; l_i[sub] = 0.f;
        #pragma unroll
        for (int ct = 0; ct < 4; ct++) acc_o[sub][ct] = (f32x4){0.f, 0.f, 0.f, 0.f};
    }

    for (int kt = 0; kt < S_; kt += 128) {
        // ---- stage K tile [128 key][64 hd] and Vt tile [64 hd][128 key] ----
        #pragma unroll
        for (int p = 0; p < 4; p++) {
            int idx = tid + p * 256;
            int kr = idx >> 3, kc = (idx & 7) * 8;      // K
            *reinterpret_cast<uint4*>(&Ks[kr][kc]) =
                *reinterpret_cast<const uint4*>(K + kbase + (size_t)(kt + kr) * HD_ + kc);
            int vr = idx >> 4, vc = (idx & 15) * 8;     // Vt
            *reinterpret_cast<uint4*>(&Vts[vr][vc]) =
                *reinterpret_cast<const uint4*>(Vt + vbase + (size_t)vr * S_ + kt + vc);
        }
        __syncthreads();

        // ---- S^T = K·Q^T : wave's 32 q-cols x 128 key-rows ----
        f32x4 st[2][8];
        #pragma unroll
        for (int sub = 0; sub < 2; sub++)
            #pragma unroll
            for (int t8 = 0; t8 < 8; t8++) st[sub][t8] = (f32x4){0.f, 0.f, 0.f, 0.f};
        #pragma unroll
        for (int ks = 0; ks < 2; ks++) {
            bf16x8 kf[8];
            #pragma unroll
            for (int t8 = 0; t8 < 8; t8++)
                kf[t8] = *reinterpret_cast<const bf16x8*>(&Ks[t8*16 + c][ks*32 + g*8]);
            #pragma unroll
            for (int sub = 0; sub < 2; sub++)
                #pragma unroll
                for (int t8 = 0; t8 < 8; t8++)
                    st[sub][t8] = __builtin_amdgcn_mfma_f32_16x16x32_bf16(kf[t8], qf[sub][ks], st[sub][t8], 0, 0, 0);
        }

        // ---- online softmax in exp2 domain; lane owns q = c (per subtile) ----
        float alpha[2];
        #pragma unroll
        for (int sub = 0; sub < 2; sub++) {
            float mloc = -INFINITY;
            #pragma unroll
            for (int t8 = 0; t8 < 8; t8++)
                #pragma unroll
                for (int r = 0; r < 4; r++) mloc = fmaxf(mloc, st[sub][t8][r]);
            mloc = fmaxf(mloc, __shfl_xor(mloc, 16));
            mloc = fmaxf(mloc, __shfl_xor(mloc, 32));
            float mnew = fmaxf(m_i[sub], mloc);
            alpha[sub] = exp2f(m_i[sub] - mnew);
            m_i[sub] = mnew;
            float rs = 0.f;
            #pragma unroll
            for (int t8 = 0; t8 < 8; t8++) {
                float p0 = exp2f(st[sub][t8][0] - mnew);
                float p1 = exp2f(st[sub][t8][1] - mnew);
                float p2 = exp2f(st[sub][t8][2] - mnew);
                float p3 = exp2f(st[sub][t8][3] - mnew);
                rs += (p0 + p1) + (p2 + p3);
                ushort4 pk;
                pk.x = f2bf(p0); pk.y = f2bf(p1); pk.z = f2bf(p2); pk.w = f2bf(p3);
                *reinterpret_cast<ushort4*>(&Ps[w*32 + sub*16 + c][t8*16 + g*4]) = pk;  // b64
            }
            rs += __shfl_xor(rs, 16);
            rs += __shfl_xor(rs, 32);
            l_i[sub] = l_i[sub] * alpha[sub] + rs;
        }

        // ---- rescale O by alpha (alpha for q-row g*4+r lives in lane g*4+r) ----
        #pragma unroll
        for (int sub = 0; sub < 2; sub++) {
            #pragma unroll
            for (int r = 0; r < 4; r++) {
                float ar = __shfl(alpha[sub], g*4 + r);
                #pragma unroll
                for (int ct = 0; ct < 4; ct++) acc_o[sub][ct][r] *= ar;
            }
        }

        // ---- O += P·V : A-frag = Ps[q][key], B-frag = Vts[hd][key] ----
        #pragma unroll
        for (int k4 = 0; k4 < 4; k4++) {
            bf16x8 pf[2], vf[4];
            #pragma unroll
            for (int sub = 0; sub < 2; sub++)
                pf[sub] = *reinterpret_cast<const bf16x8*>(&Ps[w*32 + sub*16 + c][k4*32 + g*8]);
            #pragma unroll
            for (int ct = 0; ct < 4; ct++)
                vf[ct] = *reinterpret_cast<const bf16x8*>(&Vts[ct*16 + c][k4*32 + g*8]);
            #pragma unroll
            for (int sub = 0; sub < 2; sub++)
                #pragma unroll
                for (int ct = 0; ct < 4; ct++)
                    acc_o[sub][ct] = __builtin_amdgcn_mfma_f32_16x16x32_bf16(pf[sub], vf[ct], acc_o[sub][ct], 0, 0, 0);
        }
        __syncthreads();   // protect Ks/Vts before next tile's staging
    }

    const int b = bh >> 4, h = bh & 15;
    #pragma unroll
    for (int sub = 0; sub < 2; sub++)
        #pragma unroll
        for (int r = 0; r < 4; r++) {
            float lr = 1.f / __shfl(l_i[sub], g*4 + r);
            int s = q0 + w*32 + sub*16 + g*4 + r;
            #pragma unroll
            for (int ct = 0; ct < 4; ct++)
                O[(size_t)(b*S_ + s) * 1024 + h*64 + ct*16 + c] = f2bf(acc_o[sub][ct][r] * lr);
        }
}

extern "C" void kernel_launch(void* const* d_in, const int* in_sizes, int n_in,
                              void* d_out, int out_size, void* d_ws, size_t ws_size,
                              hipStream_t stream)
{
    const float* x  = (const float*)d_in[0];
    const float* wq = (const float*)d_in[1];
    const float* bq = (const float*)d_in[2];
    const float* wk = (const float*)d_in[3];
    const float* bk = (const float*)d_in[4];
    const float* wv = (const float*)d_in[5];
    const float* bv = (const float*)d_in[6];
    const float* wo = (const float*)d_in[7];
    const float* bo = (const float*)d_in[8];
    float* out = (float*)d_out;

    char* ws = (char*)d_ws;
    ushort* xb    = (ushort*)(ws);                      // 8 MB  x bf16; reused as vtw after gemm1
    ushort* wqkvT = (ushort*)(ws + (8ull  << 20));      // 6 MB  [3072][1024]
    ushort* woT   = (ushort*)(ws + (14ull << 20));      // 2 MB
    ushort* qw    = (ushort*)(ws + (16ull << 20));      // 8 MB  [bh][s][hd]
    ushort* kw    = (ushort*)(ws + (24ull << 20));      // 8 MB
    ushort* vw    = (ushort*)(ws + (32ull << 20));      // 8 MB  [bh][s][hd]
    ushort* ao    = (ushort*)(ws + (40ull << 20));      // 8 MB
    ushort* vtw   = xb;                                 // [bh][hd][s], reuses xb region

    convert_f32_bf16<<<4096, 256, 0, stream>>>(x, xb, M_ * D_);
    dim3 tb(32, 8);
    transpose_f32_to_bf16<<<dim3(32, 32), tb, 0, stream>>>(wq, wqkvT,               1024, 1024);
    transpose_f32_to_bf16<<<dim3(32, 32), tb, 0, stream>>>(wk, wqkvT + 1024*1024,   1024, 1024);
    transpose_f32_to_bf16<<<dim3(32, 32), tb, 0, stream>>>(wv, wqkvT + 2*1024*1024, 1024, 1024);
    transpose_f32_to_bf16<<<dim3(32, 32), tb, 0, stream>>>(wo, woT,                 1024, 1024);

    // QKV: M=4096, N=3072, K=1024
    gemm_bt<0><<<dim3(24, 32), 256, 0, stream>>>(xb, wqkvT, M_, 3072, 1024,
                                                 qw, kw, vw, bq, bk, bv, nullptr, nullptr);
    // V -> V^T per head (xb no longer needed)
    transpose_v<<<dim3(32, 32), 256, 0, stream>>>(vw, vtw);
    // attention
    attn_kernel<<<dim3(16, 32), 256, 0, stream>>>(qw, kw, vtw, ao);
    // out proj: M=4096, N=1024, K=1024
    gemm_bt<1><<<dim3(8, 32), 256, 0, stream>>>(ao, woT, M_, 1024, 1024,
                                                nullptr, nullptr, nullptr, nullptr, nullptr, nullptr,
                                                out, bo);
}